// Round 2
// baseline (7015.988 us; speedup 1.0000x reference)
//
#include <hip/hip_runtime.h>
#include <stdint.h>

#define B_  32
#define S_  512
#define D_  1024
#define H_  16
#define HD_ 64
#define L_  6
#define T_  (B_*S_)

typedef unsigned short u16;
typedef __bf16 bf16x8 __attribute__((ext_vector_type(8)));
typedef float  f32x4  __attribute__((ext_vector_type(4)));
typedef u16    u16x4  __attribute__((ext_vector_type(4)));
typedef u16    u16x8  __attribute__((ext_vector_type(8)));

__device__ __forceinline__ float bf2f(u16 h){
  union { unsigned u; float f; } v; v.u = ((unsigned)h) << 16; return v.f;
}
__device__ __forceinline__ u16 f2bf(float f){
  union { float f; unsigned u; } v; v.f = f;
  unsigned r = v.u + 0x7FFFu + ((v.u >> 16) & 1u);
  return (u16)(r >> 16);
}
__device__ __forceinline__ float gelu_f(float x){
  return 0.5f * x * (1.0f + erff(x * 0.7071067811865475f));
}
__device__ __forceinline__ void gload_lds16(const void* g, void* l){
  __builtin_amdgcn_global_load_lds((const __attribute__((address_space(1))) void*)g,
                                   (__attribute__((address_space(3))) void*)l, 16, 0, 0);
}
__device__ __forceinline__ f32x4 mfma16(bf16x8 a, bf16x8 b, f32x4 c){
  return __builtin_amdgcn_mfma_f32_16x16x32_bf16(a, b, c, 0, 0, 0);
}

// ---------------- weight transpose + f32->bf16:  W (K x N) -> Wt (N x K) ----
__global__ void wconv_t(const float* __restrict__ W, u16* __restrict__ Wt, int K, int N){
  __shared__ float tile[32][33];
  const int n0 = blockIdx.x * 32, k0 = blockIdx.y * 32;
  const int tx = threadIdx.x, ty = threadIdx.y;      // block (32,8)
#pragma unroll
  for(int i = 0; i < 32; i += 8)
    tile[ty + i][tx] = W[(size_t)(k0 + ty + i) * N + n0 + tx];
  __syncthreads();
#pragma unroll
  for(int i = 0; i < 32; i += 8)
    Wt[(size_t)(n0 + ty + i) * K + k0 + tx] = f2bf(tile[tx][ty + i]);
}

// ---------------- f32 -> bf16 elementwise (vectorized) ----------------------
__global__ void f2bf4_k(const float* __restrict__ in, u16* __restrict__ out, int n){
  int i = (blockIdx.x * 256 + threadIdx.x) * 4;
  if(i < n){
    f32x4 v = *(const f32x4*)(in + i);
    u16x4 o;
#pragma unroll
    for(int j = 0; j < 4; j++) o[j] = f2bf(v[j]);
    *(u16x4*)(out + i) = o;
  }
}

// ---------------- RoPE tables ----------------------------------------------
__global__ void rope_tab_k(float* __restrict__ ct, float* __restrict__ st){
  int i = blockIdx.x * 256 + threadIdx.x;       // S*32 threads
  int s = i >> 5, j = i & 31;
  float inv = expf(-((float)(2 * j) * (1.0f / 64.0f)) * 9.210340371976184f); // ln(1e4)
  float ang = (float)s * inv;
  ct[i] = cosf(ang);
  st[i] = sinf(ang);
}

// ---------------- RoPE in-place on bf16 q,k --------------------------------
__global__ void rope_k(u16* __restrict__ q, u16* __restrict__ k,
                       const float* __restrict__ ct, const float* __restrict__ st){
  int idx = blockIdx.x * 256 + threadIdx.x;     // T*H*32 threads
  int i = idx & 31, hh = (idx >> 5) & 15, t = idx >> 9;
  int s = t & (S_ - 1);
  size_t base = ((size_t)t * H_ + hh) * HD_;
  float c = ct[s * 32 + i], sn = st[s * 32 + i];
  float x1 = bf2f(q[base + i]), x2 = bf2f(q[base + 32 + i]);
  q[base + i]      = f2bf(x1 * c - x2 * sn);
  q[base + 32 + i] = f2bf(x1 * sn + x2 * c);
  x1 = bf2f(k[base + i]); x2 = bf2f(k[base + 32 + i]);
  k[base + i]      = f2bf(x1 * c - x2 * sn);
  k[base + 32 + i] = f2bf(x1 * sn + x2 * c);
}

// ---------------- V transpose: (b,s,h,hd) -> (b,h,hd,s) --------------------
__global__ __launch_bounds__(256) void vtrans_k(const u16* __restrict__ v, u16* __restrict__ vt){
  __shared__ u16 t[64][65];
  const int st = blockIdx.x * 64, h = blockIdx.y, b = blockIdx.z;
  const int tid = threadIdx.x;
#pragma unroll
  for(int p = 0; p < 2; p++){
    int r = p * 32 + (tid >> 3), c0 = (tid & 7) * 8;
    u16x8 x = *(const u16x8*)(v + ((size_t)(b * S_ + st + r) * H_ + h) * HD_ + c0);
#pragma unroll
    for(int j = 0; j < 8; j++) t[r][c0 + j] = x[j];
  }
  __syncthreads();
#pragma unroll
  for(int p = 0; p < 2; p++){
    int r = p * 32 + (tid >> 3), c0 = (tid & 7) * 8;
    u16x8 x;
#pragma unroll
    for(int j = 0; j < 8; j++) x[j] = t[c0 + j][r];
    *(u16x8*)(vt + ((size_t)(b * H_ + h) * HD_ + r) * S_ + st + c0) = x;
  }
}

// ---------------- GEMM: C[M,N] = A[M,K] @ Bt[N,K]^T + bias ------------------
// EPI: 0 = bf16 out, 1 = gelu->bf16 out, 2 = f32 out
template<int EPI>
__global__ __launch_bounds__(256) void gemm_bt(
    const u16* __restrict__ A, const u16* __restrict__ Bt,
    const float* __restrict__ bias, void* __restrict__ C,
    int M, int N, int K)
{
  __shared__ u16 As[128 * 32];
  __shared__ u16 Bs[128 * 32];
  const int tid = threadIdx.x;
  const int w = tid >> 6, l = tid & 63;
  const int lr = l & 15, lg = l >> 4;
  const int m0 = blockIdx.y * 128, n0 = blockIdx.x * 128;
  const int wr = w >> 1, wc = w & 1;

  const f32x4 z4 = {0.f, 0.f, 0.f, 0.f};
  f32x4 acc[4][4];
#pragma unroll
  for(int i = 0; i < 4; i++)
#pragma unroll
    for(int j = 0; j < 4; j++) acc[i][j] = z4;

  // staging: lane covers linear LDS bytes; logical col-group is 2-bit XOR swizzled
  const int srow = l >> 2;                       // 0..15
  const int sc0  = ((l & 3) ^ (srow & 3)) * 8;   // swizzled source col (elems)

  for(int k0 = 0; k0 < K; k0 += 32){
    {
      int ra  = m0 + w * 16 + srow;       if(ra  >= M) ra  = M - 1;
      int ra2 = m0 + w * 16 + 64 + srow;  if(ra2 >= M) ra2 = M - 1;
      gload_lds16(A  + (size_t)ra  * K + k0 + sc0, (char*)As + (w * 16) * 64);
      gload_lds16(A  + (size_t)ra2 * K + k0 + sc0, (char*)As + (w * 16 + 64) * 64);
      gload_lds16(Bt + (size_t)(n0 + w * 16 + srow)      * K + k0 + sc0, (char*)Bs + (w * 16) * 64);
      gload_lds16(Bt + (size_t)(n0 + w * 16 + 64 + srow) * K + k0 + sc0, (char*)Bs + (w * 16 + 64) * 64);
    }
    __syncthreads();
    bf16x8 af[4], bfr[4];
#pragma unroll
    for(int i = 0; i < 4; i++){
      int rowa = wr * 64 + i * 16 + lr;
      af[i]  = *(const bf16x8*)((const char*)As + rowa * 64 + ((lg ^ (rowa & 3)) << 4));
      int rowb = wc * 64 + i * 16 + lr;
      bfr[i] = *(const bf16x8*)((const char*)Bs + rowb * 64 + ((lg ^ (rowb & 3)) << 4));
    }
#pragma unroll
    for(int i = 0; i < 4; i++)
#pragma unroll
      for(int j = 0; j < 4; j++)
        acc[i][j] = mfma16(af[i], bfr[j], acc[i][j]);
    __syncthreads();
  }

#pragma unroll
  for(int j = 0; j < 4; j++){
    int col = n0 + wc * 64 + j * 16 + lr;
    float bv = bias[col];
#pragma unroll
    for(int i = 0; i < 4; i++){
      int row0 = m0 + wr * 64 + i * 16 + lg * 4;
#pragma unroll
      for(int r = 0; r < 4; r++){
        int row = row0 + r;
        if(row < M){
          float v = acc[i][j][r] + bv;
          if(EPI == 1) v = gelu_f(v);
          if(EPI == 2) ((float*)C)[(size_t)row * N + col] = v;
          else         ((u16*)C)[(size_t)row * N + col]   = f2bf(v);
        }
      }
    }
  }
}

// ---------------- flash attention ------------------------------------------
// q,k: (b,s,h,hd) bf16 (rope applied); vt: (b,h,hd,s) bf16; out: (b,s,h,hd)
__global__ __launch_bounds__(256) void flash_attn(
    const u16* __restrict__ qg, const u16* __restrict__ kg,
    const u16* __restrict__ vt, u16* __restrict__ og,
    const int* __restrict__ lengths)
{
  __shared__ u16 Ks[64 * 64];       // logical [kpos][hd], XOR-swizzled rows
  __shared__ u16 Vs[64 * 64];       // logical [hd][kpos], XOR-swizzled rows
  __shared__ u16 Ps[4][32 * 64];    // per-wave [q][kpos], XOR-swizzled rows
  const int qt = blockIdx.x, h = blockIdx.y, b = blockIdx.z;
  const int tid = threadIdx.x, w = tid >> 6, l = tid & 63;
  const int lr = l & 15, lg = l >> 4;
  const int len = lengths[b];
  const int q0 = qt * 128 + w * 32;
  const f32x4 z4 = {0.f, 0.f, 0.f, 0.f};

  bf16x8 qf[2][2];
#pragma unroll
  for(int mi = 0; mi < 2; mi++)
#pragma unroll
    for(int c = 0; c < 2; c++){
      int qrow = q0 + mi * 16 + lr;
      qf[mi][c] = *(const bf16x8*)(qg + ((size_t)(b * S_ + qrow) * H_ + h) * HD_ + c * 32 + lg * 8);
    }

  f32x4 o[2][4];
  float mr[2][4], ls[2][4];
#pragma unroll
  for(int mi = 0; mi < 2; mi++){
#pragma unroll
    for(int n = 0; n < 4; n++) o[mi][n] = z4;
#pragma unroll
    for(int r = 0; r < 4; r++){ mr[mi][r] = -1e30f; ls[mi][r] = 0.f; }
  }
  int ktend = qt * 2 + 1;
  int ktl = (len - 1) >> 6;
  if(ktl < ktend) ktend = ktl;
  const float scale = 0.125f;

  for(int kt = 0; kt <= ktend; kt++){
    __syncthreads();
#pragma unroll
    for(int i = 0; i < 2; i++){
      int y  = i * 4096 + w * 1024 + l * 16;   // linear LDS byte this lane fills
      int rr = y >> 7;                          // 128B row
      int xb = (y & 127) ^ ((rr & 7) << 4);     // inverse-swizzled in-row byte
      gload_lds16(kg + ((size_t)(b * S_ + kt * 64 + rr) * H_ + h) * HD_ + (xb >> 1),
                  (char*)Ks + i * 4096 + w * 1024);
      gload_lds16(vt + ((size_t)(b * H_ + h) * HD_ + rr) * S_ + kt * 64 + (xb >> 1),
                  (char*)Vs + i * 4096 + w * 1024);
    }
    __syncthreads();

    // QK^T
    f32x4 sc[2][4];
#pragma unroll
    for(int mi = 0; mi < 2; mi++)
#pragma unroll
      for(int n = 0; n < 4; n++) sc[mi][n] = z4;
#pragma unroll
    for(int n = 0; n < 4; n++){
      int kr = n * 16 + lr;
#pragma unroll
      for(int c = 0; c < 2; c++){
        bf16x8 kf = *(const bf16x8*)((const char*)Ks + ((kr * 128 + c * 64 + lg * 16) ^ ((kr & 7) << 4)));
        sc[0][n] = mfma16(qf[0][c], kf, sc[0][n]);
        sc[1][n] = mfma16(qf[1][c], kf, sc[1][n]);
      }
    }
    // scale + mask + row max
    float pmax[2][4];
#pragma unroll
    for(int mi = 0; mi < 2; mi++)
#pragma unroll
      for(int r = 0; r < 4; r++) pmax[mi][r] = -1e30f;
#pragma unroll
    for(int mi = 0; mi < 2; mi++)
#pragma unroll
      for(int n = 0; n < 4; n++){
        int kpos = kt * 64 + n * 16 + lr;
#pragma unroll
        for(int r = 0; r < 4; r++){
          int qrow = q0 + mi * 16 + lg * 4 + r;
          float v = sc[mi][n][r] * scale;
          bool ok = (kpos <= qrow) && (kpos < len);
          v = ok ? v : -1e30f;
          sc[mi][n][r] = v;
          pmax[mi][r] = fmaxf(pmax[mi][r], v);
        }
      }
#pragma unroll
    for(int mi = 0; mi < 2; mi++)
#pragma unroll
      for(int r = 0; r < 4; r++){
        float v = pmax[mi][r];
        v = fmaxf(v, __shfl_xor(v, 1));
        v = fmaxf(v, __shfl_xor(v, 2));
        v = fmaxf(v, __shfl_xor(v, 4));
        v = fmaxf(v, __shfl_xor(v, 8));
        pmax[mi][r] = v;
      }
    float alpha[2][4];
#pragma unroll
    for(int mi = 0; mi < 2; mi++)
#pragma unroll
      for(int r = 0; r < 4; r++){
        float mnew = fmaxf(mr[mi][r], pmax[mi][r]);
        alpha[mi][r] = __expf(mr[mi][r] - mnew);
        mr[mi][r] = mnew;
      }
    // P = exp(sc - m), write to per-wave swizzled LDS, accumulate row sums
    float rs[2][4];
#pragma unroll
    for(int mi = 0; mi < 2; mi++)
#pragma unroll
      for(int r = 0; r < 4; r++) rs[mi][r] = 0.f;
#pragma unroll
    for(int mi = 0; mi < 2; mi++)
#pragma unroll
      for(int n = 0; n < 4; n++)
#pragma unroll
        for(int r = 0; r < 4; r++){
          float p = __expf(sc[mi][n][r] - mr[mi][r]);
          rs[mi][r] += p;
          int q = mi * 16 + lg * 4 + r;
          int xb = (q * 128 + (n * 16 + lr) * 2) ^ ((q & 7) << 4);
          *(u16*)((char*)Ps[w] + xb) = f2bf(p);
        }
#pragma unroll
    for(int mi = 0; mi < 2; mi++)
#pragma unroll
      for(int r = 0; r < 4; r++){
        float v = rs[mi][r];
        v += __shfl_xor(v, 1); v += __shfl_xor(v, 2);
        v += __shfl_xor(v, 4); v += __shfl_xor(v, 8);
        ls[mi][r] = ls[mi][r] * alpha[mi][r] + v;
      }
#pragma unroll
    for(int mi = 0; mi < 2; mi++)
#pragma unroll
      for(int n = 0; n < 4; n++)
#pragma unroll
        for(int r = 0; r < 4; r++) o[mi][n][r] *= alpha[mi][r];
    // PV
#pragma unroll
    for(int c = 0; c < 2; c++){
      bf16x8 pf[2];
#pragma unroll
      for(int mi = 0; mi < 2; mi++){
        int q = mi * 16 + lr;
        pf[mi] = *(const bf16x8*)((const char*)Ps[w] + ((q * 128 + c * 64 + lg * 16) ^ ((q & 7) << 4)));
      }
#pragma unroll
      for(int n = 0; n < 4; n++){
        int hd = n * 16 + lr;
        bf16x8 vf = *(const bf16x8*)((const char*)Vs + ((hd * 128 + c * 64 + lg * 16) ^ ((hd & 7) << 4)));
        o[0][n] = mfma16(pf[0], vf, o[0][n]);
        o[1][n] = mfma16(pf[1], vf, o[1][n]);
      }
    }
  }
  // write
#pragma unroll
  for(int mi = 0; mi < 2; mi++)
#pragma unroll
    for(int n = 0; n < 4; n++)
#pragma unroll
      for(int r = 0; r < 4; r++){
        int qrow = q0 + mi * 16 + lg * 4 + r;
        int hd = n * 16 + lr;
        og[((size_t)(b * S_ + qrow) * H_ + h) * HD_ + hd] = f2bf(o[mi][n][r] / ls[mi][r]);
      }
}

// ---------------- residual + LayerNorm (+mask), writes f32 + bf16 ----------
template<int RESID, int MASK>
__global__ __launch_bounds__(256) void ln_k(
    const float* __restrict__ y, float* __restrict__ x,
    const float* __restrict__ g, const float* __restrict__ bb,
    u16* __restrict__ xb, const int* __restrict__ lengths)
{
  const int row = blockIdx.x, tid = threadIdx.x;
  const float* yr = y + (size_t)row * D_;
  float* xr = x + (size_t)row * D_;
  float v[4]; float s1 = 0.f, s2 = 0.f;
#pragma unroll
  for(int i = 0; i < 4; i++){
    float t = yr[tid + i * 256];
    if(RESID) t += xr[tid + i * 256];
    v[i] = t; s1 += t; s2 += t * t;
  }
#pragma unroll
  for(int off = 32; off > 0; off >>= 1){ s1 += __shfl_down(s1, off); s2 += __shfl_down(s2, off); }
  __shared__ float red[8];
  if((tid & 63) == 0){ red[tid >> 6] = s1; red[4 + (tid >> 6)] = s2; }
  __syncthreads();
  s1 = red[0] + red[1] + red[2] + red[3];
  s2 = red[4] + red[5] + red[6] + red[7];
  const float mean = s1 * (1.f / D_);
  float var = s2 * (1.f / D_) - mean * mean;
  const float rstd = rsqrtf(var + 1e-5f);
  float m = 1.f;
  if(MASK){ int s = row & (S_ - 1); int bi = row >> 9; m = (s < lengths[bi]) ? 1.f : 0.f; }
  u16* xbr = xb + (size_t)row * D_;
#pragma unroll
  for(int i = 0; i < 4; i++){
    int c = tid + i * 256;
    float o = ((v[i] - mean) * rstd * g[c] + bb[c]) * m;
    xr[c] = o; xbr[c] = f2bf(o);
  }
}

// ---------------- summary gather -------------------------------------------
__global__ void gather_k(const u16* __restrict__ xb, const int* __restrict__ lengths,
                         u16* __restrict__ sb){
  int b = blockIdx.x, tid = threadIdx.x;
  int pos = lengths[b] - 1; if(pos < 0) pos = 0; if(pos > S_ - 1) pos = S_ - 1;
  const u16* src = xb + (size_t)(b * S_ + pos) * D_;
  u16* dst = sb + (size_t)b * D_;
  for(int i = tid; i < D_; i += 256) dst[i] = src[i];
}

// ---------------- final heads (pol_W2: 2048x11, val_W2: 2048x1) -------------
__global__ __launch_bounds__(256) void head_out_k(
    const u16* __restrict__ gp, const u16* __restrict__ gv,
    const float* __restrict__ pw2, const float* __restrict__ pb2,
    const float* __restrict__ vw2, const float* __restrict__ vb2,
    float* __restrict__ out)
{
  const int b = blockIdx.x, tid = threadIdx.x;
  float acc[12];
#pragma unroll
  for(int j = 0; j < 12; j++) acc[j] = 0.f;
  for(int k = tid; k < 2048; k += 256){
    float gpv = bf2f(gp[b * 2048 + k]);
#pragma unroll
    for(int j = 0; j < 11; j++) acc[j] += gpv * pw2[k * 11 + j];
    acc[11] += bf2f(gv[b * 2048 + k]) * vw2[k];
  }
  __shared__ float buf[256];
  for(int j = 0; j < 12; j++){
    buf[tid] = acc[j]; __syncthreads();
    for(int s = 128; s > 0; s >>= 1){ if(tid < s) buf[tid] += buf[tid + s]; __syncthreads(); }
    if(tid == 0) out[b * 12 + j] = buf[0] + (j < 11 ? pb2[j] : vb2[0]);
    __syncthreads();
  }
}

// ============================================================================
extern "C" void kernel_launch(void* const* d_in, const int* in_sizes, int n_in,
                              void* d_out, int out_size, void* d_ws, size_t ws_size,
                              hipStream_t stream)
{
  const float* emb     = (const float*)d_in[0];
  const float* in_W1   = (const float*)d_in[1];
  const float* in_b1   = (const float*)d_in[2];
  const float* in_W2   = (const float*)d_in[3];
  const float* in_b2   = (const float*)d_in[4];
  const float* in_ln_g = (const float*)d_in[5];
  const float* in_ln_b = (const float*)d_in[6];
  const float* Wq = (const float*)d_in[7];
  const float* bq = (const float*)d_in[8];
  const float* Wk = (const float*)d_in[9];
  const float* bk = (const float*)d_in[10];
  const float* Wv = (const float*)d_in[11];
  const float* bv = (const float*)d_in[12];
  const float* Wo = (const float*)d_in[13];
  const float* bo = (const float*)d_in[14];
  const float* n1_g = (const float*)d_in[15];
  const float* n1_b = (const float*)d_in[16];
  const float* n2_g = (const float*)d_in[17];
  const float* n2_b = (const float*)d_in[18];
  const float* f_W1 = (const float*)d_in[19];
  const float* f_b1 = (const float*)d_in[20];
  const float* f_W2 = (const float*)d_in[21];
  const float* f_b2 = (const float*)d_in[22];
  const float* cls_W1   = (const float*)d_in[23];
  const float* cls_b1   = (const float*)d_in[24];
  const float* cls_W2   = (const float*)d_in[25];
  const float* cls_b2   = (const float*)d_in[26];
  const float* cls_ln_g = (const float*)d_in[27];
  const float* cls_ln_b = (const float*)d_in[28];
  const float* pol_W1 = (const float*)d_in[29];
  const float* pol_b1 = (const float*)d_in[30];
  const float* pol_W2 = (const float*)d_in[31];
  const float* pol_b2 = (const float*)d_in[32];
  const float* val_W1 = (const float*)d_in[33];
  const float* val_b1 = (const float*)d_in[34];
  const float* val_W2 = (const float*)d_in[35];
  const float* val_b2 = (const float*)d_in[36];
  const int*   lengths = (const int*)d_in[37];

  // ---- workspace plan (lifetime-aliased; ~313 MB total) --------------------
  char* base = (char*)d_ws; size_t off = 0;
  auto carve = [&](size_t n) -> char* {
    char* r = base + off; off = (off + n + 255) & ~(size_t)255; return r;
  };

  // reusable weight slots (converted per use, stream-ordered)
  u16* slotF1 = (u16*)carve(4096ull * 1024 * 2);   // 8 MB (f_W1 / in_W1 / cls_W1 / pol_W1)
  u16* slotF2 = (u16*)carve(4096ull * 1024 * 2);   // 8 MB (f_W2 / in_W2 / cls_W2 / val_W1)
  u16* slotQ  = (u16*)carve(1024ull * 1024 * 2);   // 2 MB
  u16* slotK  = (u16*)carve(1024ull * 1024 * 2);
  u16* slotV  = (u16*)carve(1024ull * 1024 * 2);
  u16* slotO  = (u16*)carve(1024ull * 1024 * 2);

  float* ct = (float*)carve(S_ * 32 * 4);
  float* st = (float*)carve(S_ * 32 * 4);

  u16*   xb   = (u16*)carve((size_t)T_ * D_ * 2);      // 32 MB  bf16 stream
  float* x    = (float*)carve((size_t)T_ * D_ * 4);    // 64 MB  f32 residual
  float* y    = (float*)carve((size_t)T_ * D_ * 4);    // 64 MB  f32 gemm out

  // big region: FFN intermediate ALIASES attention q/k/v/vt (never live together)
  char*  big  = carve((size_t)T_ * 4096 * 2);          // 128 MB
  u16*   gbuf = (u16*)big;                             // T x 4096 (FFN1 out) / T x 2048 (MLP1 out)
  u16*   qb   = (u16*)big;
  u16*   kb   = (u16*)(big + 1ull * T_ * D_ * 2);
  u16*   vb   = (u16*)(big + 2ull * T_ * D_ * 2);
  u16*   vtb  = (u16*)(big + 3ull * T_ * D_ * 2);
  u16*   aob  = vb;   // V dead once transposed; flash reads vtb, writes here

  u16*   sbuf = (u16*)carve(32ull * 1024 * 2);
  u16*   gc   = (u16*)carve(32ull * 2048 * 2);
  float* yh   = (float*)carve(32ull * 1024 * 4);
  float* sxf  = (float*)carve(32ull * 1024 * 4);
  u16*   sb2  = (u16*)carve(32ull * 1024 * 2);
  u16*   gp   = (u16*)carve(32ull * 2048 * 2);
  u16*   gv   = (u16*)carve(32ull * 2048 * 2);
  (void)in_sizes; (void)n_in; (void)out_size;

  if(off > ws_size) return;   // diagnosable: leaves poisoned d_out, no fault

  auto convT = [&](const float* W, u16* Wt, int K, int N){
    wconv_t<<<dim3(N / 32, K / 32), dim3(32, 8), 0, stream>>>(W, Wt, K, N);
  };
  auto gemm = [&](const u16* A, const u16* Bt, const float* bias, void* C,
                  int M, int N, int K, int epi){
    dim3 g(N / 128, (M + 127) / 128);
    if(epi == 0)      gemm_bt<0><<<g, 256, 0, stream>>>(A, Bt, bias, C, M, N, K);
    else if(epi == 1) gemm_bt<1><<<g, 256, 0, stream>>>(A, Bt, bias, C, M, N, K);
    else              gemm_bt<2><<<g, 256, 0, stream>>>(A, Bt, bias, C, M, N, K);
  };

  rope_tab_k<<<S_ * 32 / 256, 256, 0, stream>>>(ct, st);

  // ---- input MLP + LN + mask ----
  convT(in_W1, slotF1, 1024, 2048);
  convT(in_W2, slotF2, 2048, 1024);
  f2bf4_k<<<(T_ * D_) / 1024, 256, 0, stream>>>(emb, xb, T_ * D_);
  gemm(xb, slotF1, in_b1, gbuf, T_, 2048, 1024, 1);
  gemm(gbuf, slotF2, in_b2, y, T_, 1024, 2048, 2);
  ln_k<0, 1><<<T_, 256, 0, stream>>>(y, x, in_ln_g, in_ln_b, xb, lengths);

  // ---- transformer layers ----
  for(int l = 0; l < L_; l++){
    convT(Wq + (size_t)l * 1024 * 1024, slotQ, 1024, 1024);
    convT(Wk + (size_t)l * 1024 * 1024, slotK, 1024, 1024);
    convT(Wv + (size_t)l * 1024 * 1024, slotV, 1024, 1024);
    convT(Wo + (size_t)l * 1024 * 1024, slotO, 1024, 1024);
    gemm(xb, slotQ, bq + l * 1024, qb, T_, 1024, 1024, 0);
    gemm(xb, slotK, bk + l * 1024, kb, T_, 1024, 1024, 0);
    gemm(xb, slotV, bv + l * 1024, vb, T_, 1024, 1024, 0);
    rope_k<<<(T_ * H_ * 32) / 256, 256, 0, stream>>>(qb, kb, ct, st);
    vtrans_k<<<dim3(S_ / 64, H_, B_), 256, 0, stream>>>(vb, vtb);
    flash_attn<<<dim3(S_ / 128, H_, B_), 256, 0, stream>>>(qb, kb, vtb, aob, lengths);
    gemm(aob, slotO, bo + l * 1024, y, T_, 1024, 1024, 2);
    ln_k<1, 0><<<T_, 256, 0, stream>>>(y, x, n1_g + l * 1024, n1_b + l * 1024, xb, lengths);
    convT(f_W1 + (size_t)l * 1024 * 4096, slotF1, 1024, 4096);   // after MLP/prev FFN reads
    convT(f_W2 + (size_t)l * 4096 * 1024, slotF2, 4096, 1024);
    gemm(xb, slotF1, f_b1 + l * 4096, gbuf, T_, 4096, 1024, 1);
    gemm(gbuf, slotF2, f_b2 + l * 1024, y, T_, 1024, 4096, 2);
    ln_k<1, 1><<<T_, 256, 0, stream>>>(y, x, n2_g + l * 1024, n2_b + l * 1024, xb, lengths);
  }

  // ---- heads ----
  gather_k<<<B_, 256, 0, stream>>>(xb, lengths, sbuf);
  convT(cls_W1, slotF1, 1024, 2048);
  convT(cls_W2, slotF2, 2048, 1024);
  gemm(sbuf, slotF1, cls_b1, gc, 32, 2048, 1024, 1);
  gemm(gc, slotF2, cls_b2, yh, 32, 1024, 2048, 2);
  ln_k<0, 0><<<32, 256, 0, stream>>>(yh, sxf, cls_ln_g, cls_ln_b, sb2, lengths);
  convT(pol_W1, slotF1, 1024, 2048);   // after cls1 gemm read slotF1
  convT(val_W1, slotF2, 1024, 2048);   // after cls2 gemm read slotF2
  gemm(sb2, slotF1, pol_b1, gp, 32, 2048, 1024, 1);
  gemm(sb2, slotF2, val_b1, gv, 32, 2048, 1024, 1);
  head_out_k<<<B_, 256, 0, stream>>>(gp, gv, pol_W2, pol_b2, val_W2, val_b2, (float*)d_out);
}